// Round 2
// baseline (793.068 us; speedup 1.0000x reference)
//
#include <hip/hip_runtime.h>
#include <hip/hip_bf16.h>
#include <cstdint>
#include <cstddef>

static constexpr int Sq  = 2048;
static constexpr int Dm  = 2048;
static constexpr int NH  = 32;
static constexpr int HDm = 64;
static constexpr int FFm = 8192;

typedef __bf16 bf16x8 __attribute__((ext_vector_type(8)));
typedef float  f32x4  __attribute__((ext_vector_type(4)));

__device__ __forceinline__ void async_ld16(const void* g, void* l) {
  __builtin_amdgcn_global_load_lds((const __attribute__((address_space(1))) void*)g,
                                   (__attribute__((address_space(3))) void*)l, 16, 0, 0);
}

// ---------- transpose + cast: in[K][N] f32 -> out[N][K] bf16 ----------
__global__ __launch_bounds__(256)
void tcast_kernel(const float* __restrict__ in, __hip_bfloat16* __restrict__ out,
                  int K, int N) {
  __shared__ float tile[64][65];
  const int tc = blockIdx.x * 64;  // N-dim tile base
  const int tr = blockIdx.y * 64;  // K-dim tile base
  const int cx = threadIdx.x & 63;
  const int ry = threadIdx.x >> 6;
#pragma unroll
  for (int i = 0; i < 16; ++i) {
    int r = ry + i * 4;
    tile[r][cx] = in[(size_t)(tr + r) * N + tc + cx];
  }
  __syncthreads();
#pragma unroll
  for (int i = 0; i < 16; ++i) {
    int r = ry + i * 4;
    out[(size_t)(tc + r) * K + tr + cx] = __float2bfloat16(tile[cx][r]);
  }
}

// ---------- layernorm row kernel: x f32 -> out bf16 ----------
__global__ __launch_bounds__(256)
void ln_kernel(const float* __restrict__ x, const float* __restrict__ g,
               const float* __restrict__ b, __hip_bfloat16* __restrict__ out) {
  __shared__ float red[4];
  const int t = threadIdx.x;
  const float* xr = x + (size_t)blockIdx.x * Dm;
  float v[8];
  float s = 0.f;
#pragma unroll
  for (int i = 0; i < 8; ++i) { v[i] = xr[t + i * 256]; s += v[i]; }
#pragma unroll
  for (int off = 32; off > 0; off >>= 1) s += __shfl_down(s, off, 64);
  if ((t & 63) == 0) red[t >> 6] = s;
  __syncthreads();
  const float mean = (red[0] + red[1] + red[2] + red[3]) * (1.f / Dm);
  __syncthreads();
  float vs = 0.f;
#pragma unroll
  for (int i = 0; i < 8; ++i) { float d = v[i] - mean; vs += d * d; }
#pragma unroll
  for (int off = 32; off > 0; off >>= 1) vs += __shfl_down(vs, off, 64);
  if ((t & 63) == 0) red[t >> 6] = vs;
  __syncthreads();
  const float inv = rsqrtf((red[0] + red[1] + red[2] + red[3]) * (1.f / Dm) + 1e-5f);
  __hip_bfloat16* orow = out + (size_t)blockIdx.x * Dm;
#pragma unroll
  for (int i = 0; i < 8; ++i) {
    int c = t + i * 256;
    orow[c] = __float2bfloat16((v[i] - mean) * inv * g[c] + b[c]);
  }
}

// ---------- bf16 MFMA GEMM: C[M][N] = A[M][K] @ Bt[N][K]^T + bias ----------
// EPI 0: QKV scatter (q scaled 0.125, v transposed)    EPI 1: outf = addsrc + C
// EPI 2: outb = bf16(gelu_exact(C))
template <int EPI>
__global__ __launch_bounds__(256)
void gemm_kernel(const __hip_bfloat16* __restrict__ A,
                 const __hip_bfloat16* __restrict__ Bt,
                 int N, int K,
                 const float* __restrict__ bias,
                 const float* __restrict__ addsrc,
                 float* __restrict__ outf,
                 __hip_bfloat16* __restrict__ outb,
                 __hip_bfloat16* __restrict__ qo,
                 __hip_bfloat16* __restrict__ ko,
                 __hip_bfloat16* __restrict__ vo) {
  __shared__ __align__(16) __hip_bfloat16 As[128 * 32];
  __shared__ __align__(16) __hip_bfloat16 Bs[128 * 32];
  const int t = threadIdx.x;
  const int lane = t & 63, w = t >> 6, quad = lane >> 4, l16 = lane & 15;
  const int bn = blockIdx.x, bm = blockIdx.y;
  const int wm = (w & 1) * 64, wn = (w >> 1) * 64;
  const __hip_bfloat16* Abase = A + (size_t)bm * 128 * K;
  const __hip_bfloat16* Bbase = Bt + (size_t)bn * 128 * K;
  f32x4 acc[4][4] = {};
  for (int k0 = 0; k0 < K; k0 += 32) {
#pragma unroll
    for (int j = 0; j < 2; ++j) {
      int c = j * 256 + t;
      int row = c >> 2;
      int swz = (c & 3) ^ (row & 3);                  // XOR-swizzled 16B chunk
      async_ld16(Abase + (size_t)row * K + k0 + swz * 8, As + c * 8);
      async_ld16(Bbase + (size_t)row * K + k0 + swz * 8, Bs + c * 8);
    }
    __syncthreads();
    bf16x8 af[4], bfv[4];
#pragma unroll
    for (int i = 0; i < 4; ++i) {
      int row = wm + i * 16 + l16;
      af[i] = *(const bf16x8*)(As + row * 32 + (quad ^ (row & 3)) * 8);
    }
#pragma unroll
    for (int i = 0; i < 4; ++i) {
      int row = wn + i * 16 + l16;
      bfv[i] = *(const bf16x8*)(Bs + row * 32 + (quad ^ (row & 3)) * 8);
    }
#pragma unroll
    for (int mt = 0; mt < 4; ++mt)
#pragma unroll
      for (int nt = 0; nt < 4; ++nt)
        acc[mt][nt] = __builtin_amdgcn_mfma_f32_16x16x32_bf16(af[mt], bfv[nt], acc[mt][nt], 0, 0, 0);
    __syncthreads();
  }
#pragma unroll
  for (int mt = 0; mt < 4; ++mt) {
#pragma unroll
    for (int nt = 0; nt < 4; ++nt) {
      const int n = bn * 128 + wn + nt * 16 + l16;
      const float bz = bias[n];
#pragma unroll
      for (int r = 0; r < 4; ++r) {
        const int m = bm * 128 + wm + mt * 16 + quad * 4 + r;
        float val = acc[mt][nt][r] + bz;
        if constexpr (EPI == 0) {
          int which = n >> 11, d2 = n & 2047;
          int hh = d2 >> 6, hd = d2 & 63;
          if (which == 0)
            qo[((size_t)hh * Sq + m) * HDm + hd] = __float2bfloat16(val * 0.125f);
          else if (which == 1)
            ko[((size_t)hh * Sq + m) * HDm + hd] = __float2bfloat16(val);
          else
            vo[((size_t)hh * HDm + hd) * Sq + m] = __float2bfloat16(val);
        } else if constexpr (EPI == 1) {
          outf[(size_t)m * N + n] = addsrc[(size_t)m * N + n] + val;
        } else {
          float gg = 0.5f * val * (1.0f + erff(val * 0.70710678118654752f));
          outb[(size_t)m * N + n] = __float2bfloat16(gg);
        }
      }
    }
  }
}

// ---------- flash attention: q[h][s][d] (pre-scaled), k[h][s][d], vt[h][d][s] ----------
__global__ __launch_bounds__(256)
void attn_kernel(const __hip_bfloat16* __restrict__ qb,
                 const __hip_bfloat16* __restrict__ kb,
                 const __hip_bfloat16* __restrict__ vt,
                 const float* __restrict__ alibi,
                 __hip_bfloat16* __restrict__ ctx) {
  __shared__ __align__(16) __hip_bfloat16 Kl[64 * 64];
  __shared__ __align__(16) __hip_bfloat16 Vl[64 * 64];     // [d][key]
  __shared__ __align__(16) __hip_bfloat16 Pl[4][16 * 64];  // per-wave P tile
  const int qblk = blockIdx.x, h = blockIdx.y;
  const int t = threadIdx.x, w = t >> 6, lane = t & 63, quad = lane >> 4, l16 = lane & 15;
  const __hip_bfloat16* qh = qb + (size_t)h * Sq * HDm;
  const __hip_bfloat16* kh = kb + (size_t)h * Sq * HDm;
  const __hip_bfloat16* vh = vt + (size_t)h * HDm * Sq;
  const float* al = alibi + (size_t)h * Sq;
  const int qr0 = qblk * 64 + w * 16;
  const bf16x8 qa0 = *(const bf16x8*)(qh + (size_t)(qr0 + l16) * HDm + quad * 8);
  const bf16x8 qa1 = *(const bf16x8*)(qh + (size_t)(qr0 + l16) * HDm + 32 + quad * 8);
  f32x4 o[4] = {};
  float m_i[4], l_i[4];
#pragma unroll
  for (int r = 0; r < 4; ++r) { m_i[r] = -3e38f; l_i[r] = 0.f; }
  for (int kbk = 0; kbk <= qblk; ++kbk) {
    __syncthreads();
#pragma unroll
    for (int j = 0; j < 2; ++j) {
      int c = j * 256 + t;
      int row = c >> 3;
      int swz = (c & 7) ^ (row & 7);  // XOR-swizzled 16B chunks (8 per row)
      async_ld16(kh + (size_t)(kbk * 64 + row) * HDm + swz * 8, Kl + c * 8);
      async_ld16(vh + (size_t)row * Sq + kbk * 64 + swz * 8, Vl + c * 8);
    }
    __syncthreads();
    f32x4 sf[4];
    const f32x4 zero = {};
#pragma unroll
    for (int nt = 0; nt < 4; ++nt) {
      int row = nt * 16 + l16;
      bf16x8 kf0 = *(const bf16x8*)(Kl + row * 64 + ((quad ^ (row & 7)) << 3));
      bf16x8 kf1 = *(const bf16x8*)(Kl + row * 64 + (((4 + quad) ^ (row & 7)) << 3));
      sf[nt] = __builtin_amdgcn_mfma_f32_16x16x32_bf16(qa0, kf0, zero, 0, 0, 0);
      sf[nt] = __builtin_amdgcn_mfma_f32_16x16x32_bf16(qa1, kf1, sf[nt], 0, 0, 0);
    }
    const bool diag = (kbk == qblk);
    float mrow[4] = {-3e38f, -3e38f, -3e38f, -3e38f};
#pragma unroll
    for (int nt = 0; nt < 4; ++nt) {
      const float ab = al[kbk * 64 + nt * 16 + l16] * 0.125f;
      const int kcol = nt * 16 + l16;
#pragma unroll
      for (int r = 0; r < 4; ++r) {
        float vv = sf[nt][r] + ab;
        if (diag && kcol > w * 16 + quad * 4 + r) vv = -3e38f;
        sf[nt][r] = vv;
        mrow[r] = fmaxf(mrow[r], vv);
      }
    }
#pragma unroll
    for (int off = 8; off > 0; off >>= 1)
#pragma unroll
      for (int r = 0; r < 4; ++r)
        mrow[r] = fmaxf(mrow[r], __shfl_xor(mrow[r], off, 64));
    float alpha[4], rs[4], p[4][4];
#pragma unroll
    for (int r = 0; r < 4; ++r) {
      float mn = fmaxf(m_i[r], mrow[r]);
      alpha[r] = __expf(m_i[r] - mn);
      m_i[r] = mn;
    }
#pragma unroll
    for (int nt = 0; nt < 4; ++nt)
#pragma unroll
      for (int r = 0; r < 4; ++r) p[nt][r] = __expf(sf[nt][r] - m_i[r]);
#pragma unroll
    for (int r = 0; r < 4; ++r) rs[r] = p[0][r] + p[1][r] + p[2][r] + p[3][r];
#pragma unroll
    for (int off = 8; off > 0; off >>= 1)
#pragma unroll
      for (int r = 0; r < 4; ++r) rs[r] += __shfl_xor(rs[r], off, 64);
#pragma unroll
    for (int r = 0; r < 4; ++r) l_i[r] = l_i[r] * alpha[r] + rs[r];
#pragma unroll
    for (int dt = 0; dt < 4; ++dt)
#pragma unroll
      for (int r = 0; r < 4; ++r) o[dt][r] *= alpha[r];
    // P: C/D layout -> LDS (swizzled) -> A-operand layout
    __hip_bfloat16* pw = &Pl[w][0];
#pragma unroll
    for (int nt = 0; nt < 4; ++nt)
#pragma unroll
      for (int r = 0; r < 4; ++r) {
        int prow = quad * 4 + r;
        int e = nt * 16 + l16;
        int c16 = e >> 3;
        pw[prow * 64 + ((c16 ^ (prow & 7)) << 3) + (e & 7)] = __float2bfloat16(p[nt][r]);
      }
    asm volatile("s_waitcnt lgkmcnt(0)" ::: "memory");
    const bf16x8 pa0 = *(const bf16x8*)(pw + l16 * 64 + ((quad ^ (l16 & 7)) << 3));
    const bf16x8 pa1 = *(const bf16x8*)(pw + l16 * 64 + (((4 + quad) ^ (l16 & 7)) << 3));
#pragma unroll
    for (int dt = 0; dt < 4; ++dt) {
      int row = dt * 16 + l16;
      bf16x8 v0 = *(const bf16x8*)(Vl + row * 64 + ((quad ^ (row & 7)) << 3));
      bf16x8 v1 = *(const bf16x8*)(Vl + row * 64 + (((4 + quad) ^ (row & 7)) << 3));
      o[dt] = __builtin_amdgcn_mfma_f32_16x16x32_bf16(pa0, v0, o[dt], 0, 0, 0);
      o[dt] = __builtin_amdgcn_mfma_f32_16x16x32_bf16(pa1, v1, o[dt], 0, 0, 0);
    }
  }
#pragma unroll
  for (int dt = 0; dt < 4; ++dt)
#pragma unroll
    for (int r = 0; r < 4; ++r) {
      int srow = qblk * 64 + w * 16 + quad * 4 + r;
      ctx[(size_t)srow * Dm + h * HDm + dt * 16 + l16] =
          __float2bfloat16(o[dt][r] / l_i[r]);
    }
}

extern "C" void kernel_launch(void* const* d_in, const int* in_sizes, int n_in,
                              void* d_out, int out_size, void* d_ws, size_t ws_size,
                              hipStream_t stream) {
  const float* x     = (const float*)d_in[0];
  const float* alibi = (const float*)d_in[1];
  const float* ln1g  = (const float*)d_in[3];
  const float* ln1b  = (const float*)d_in[4];
  const float* ln2g  = (const float*)d_in[5];
  const float* ln2b  = (const float*)d_in[6];
  const float* wqkv  = (const float*)d_in[7];
  const float* bqkv  = (const float*)d_in[8];
  const float* wo    = (const float*)d_in[9];
  const float* bo    = (const float*)d_in[10];
  const float* w1    = (const float*)d_in[11];
  const float* b1    = (const float*)d_in[12];
  const float* w2    = (const float*)d_in[13];
  const float* b2    = (const float*)d_in[14];
  float* out = (float*)d_out;

  // ---- workspace with lifetime-based aliasing; peak ~92 MB ----
  // R2 (33.5 MB): wqkvT -> w1T -> w2T   (weight Bt buffers, serial reuse)
  // R1 (33.6 MB): [q | k | vt | ctx] -> [woT over q slot] -> t1b
  // hb  (8.4 MB): ln1 out -> ln2 out
  // resb (16.8 MB fp32): attn residual, lives to final GEMM
  char* p = (char*)d_ws;
  auto alloc = [&](size_t bytes) {
    char* r = p;
    p += (bytes + 255) & ~(size_t)255;
    return r;
  };
  constexpr size_t SD2 = (size_t)Sq * Dm * 2;  // 8,388,608 B
  char* R2 = alloc((size_t)FFm * Dm * 2);      // 33,554,432 B
  char* R1 = alloc(4 * SD2);                   // 33,554,432 B
  __hip_bfloat16* hb   = (__hip_bfloat16*)alloc(SD2);
  float*          resb = (float*)alloc((size_t)Sq * Dm * 4);

  __hip_bfloat16* wqkvT = (__hip_bfloat16*)R2;
  __hip_bfloat16* w1T   = (__hip_bfloat16*)R2;
  __hip_bfloat16* w2T   = (__hip_bfloat16*)R2;
  __hip_bfloat16* qbuf  = (__hip_bfloat16*)(R1 + 0 * SD2);
  __hip_bfloat16* kbuf  = (__hip_bfloat16*)(R1 + 1 * SD2);
  __hip_bfloat16* vtbuf = (__hip_bfloat16*)(R1 + 2 * SD2);
  __hip_bfloat16* ctxb  = (__hip_bfloat16*)(R1 + 3 * SD2);
  __hip_bfloat16* woT   = (__hip_bfloat16*)(R1 + 0 * SD2);  // after attn
  __hip_bfloat16* t1b   = (__hip_bfloat16*)R1;              // after gemm2

  // 1) wqkv transpose+cast, ln1
  tcast_kernel<<<dim3(3 * Dm / 64, Dm / 64), 256, 0, stream>>>(wqkv, wqkvT, Dm, 3 * Dm);
  ln_kernel<<<Sq, 256, 0, stream>>>(x, ln1g, ln1b, hb);
  // 2) QKV gemm (scatters q scaled, k, v-transposed)
  gemm_kernel<0><<<dim3(3 * Dm / 128, Sq / 128), 256, 0, stream>>>(
      hb, wqkvT, 3 * Dm, Dm, bqkv, nullptr, nullptr, nullptr, qbuf, kbuf, vtbuf);
  // 3) w1 transpose into R2 (wqkvT dead after gemm above)
  tcast_kernel<<<dim3(FFm / 64, Dm / 64), 256, 0, stream>>>(w1, w1T, Dm, FFm);
  // 4) flash attention
  attn_kernel<<<dim3(Sq / 64, NH), 256, 0, stream>>>(qbuf, kbuf, vtbuf, alibi, ctxb);
  // 5) wo transpose into q slot (dead after attn)
  tcast_kernel<<<dim3(Dm / 64, Dm / 64), 256, 0, stream>>>(wo, woT, Dm, Dm);
  // 6) attn proj + residual -> resb (fp32)
  gemm_kernel<1><<<dim3(Dm / 128, Sq / 128), 256, 0, stream>>>(
      ctxb, woT, Dm, Dm, bo, x, resb, nullptr, nullptr, nullptr, nullptr);
  // 7) ln2
  ln_kernel<<<Sq, 256, 0, stream>>>(resb, ln2g, ln2b, hb);
  // 8) mlp up + gelu -> t1b (overwrites woT/ctx, both dead)
  gemm_kernel<2><<<dim3(FFm / 128, Sq / 128), 256, 0, stream>>>(
      hb, w1T, FFm, Dm, b1, nullptr, nullptr, t1b, nullptr, nullptr, nullptr);
  // 9) w2 transpose into R2 (w1T dead after gemm above)
  tcast_kernel<<<dim3(Dm / 64, FFm / 64), 256, 0, stream>>>(w2, w2T, FFm, Dm);
  // 10) mlp down + residual -> out
  gemm_kernel<1><<<dim3(Dm / 128, Sq / 128), 256, 0, stream>>>(
      t1b, w2T, Dm, FFm, b2, resb, out, nullptr, nullptr, nullptr, nullptr);
}

// Round 3
// 715.457 us; speedup vs baseline: 1.1085x; 1.1085x over previous
//
#include <hip/hip_runtime.h>
#include <hip/hip_bf16.h>
#include <cstdint>
#include <cstddef>

static constexpr int Sq  = 2048;
static constexpr int Dm  = 2048;
static constexpr int NH  = 32;
static constexpr int HDm = 64;
static constexpr int FFm = 8192;

typedef __bf16 bf16x8 __attribute__((ext_vector_type(8)));
typedef float  f32x4  __attribute__((ext_vector_type(4)));

__device__ __forceinline__ void async_ld16(const void* g, void* l) {
  __builtin_amdgcn_global_load_lds((const __attribute__((address_space(1))) void*)g,
                                   (__attribute__((address_space(3))) void*)l, 16, 0, 0);
}

// ---------- transpose + cast: in[K][N] f32 -> out[N][K] bf16 ----------
__global__ __launch_bounds__(256)
void tcast_kernel(const float* __restrict__ in, __hip_bfloat16* __restrict__ out,
                  int K, int N) {
  __shared__ float tile[64][65];
  const int tc = blockIdx.x * 64;
  const int tr = blockIdx.y * 64;
  const int cx = threadIdx.x & 63;
  const int ry = threadIdx.x >> 6;
#pragma unroll
  for (int i = 0; i < 16; ++i) {
    int r = ry + i * 4;
    tile[r][cx] = in[(size_t)(tr + r) * N + tc + cx];
  }
  __syncthreads();
#pragma unroll
  for (int i = 0; i < 16; ++i) {
    int r = ry + i * 4;
    out[(size_t)(tc + r) * K + tr + cx] = __float2bfloat16(tile[cx][r]);
  }
}

// ---------- layernorm row kernel: x f32 -> out bf16 ----------
__global__ __launch_bounds__(256)
void ln_kernel(const float* __restrict__ x, const float* __restrict__ g,
               const float* __restrict__ b, __hip_bfloat16* __restrict__ out) {
  __shared__ float red[4];
  const int t = threadIdx.x;
  const float* xr = x + (size_t)blockIdx.x * Dm;
  float v[8];
  float s = 0.f;
#pragma unroll
  for (int i = 0; i < 8; ++i) { v[i] = xr[t + i * 256]; s += v[i]; }
#pragma unroll
  for (int off = 32; off > 0; off >>= 1) s += __shfl_down(s, off, 64);
  if ((t & 63) == 0) red[t >> 6] = s;
  __syncthreads();
  const float mean = (red[0] + red[1] + red[2] + red[3]) * (1.f / Dm);
  __syncthreads();
  float vs = 0.f;
#pragma unroll
  for (int i = 0; i < 8; ++i) { float d = v[i] - mean; vs += d * d; }
#pragma unroll
  for (int off = 32; off > 0; off >>= 1) vs += __shfl_down(vs, off, 64);
  if ((t & 63) == 0) red[t >> 6] = vs;
  __syncthreads();
  const float inv = rsqrtf((red[0] + red[1] + red[2] + red[3]) * (1.f / Dm) + 1e-5f);
  __hip_bfloat16* orow = out + (size_t)blockIdx.x * Dm;
#pragma unroll
  for (int i = 0; i < 8; ++i) {
    int c = t + i * 256;
    orow[c] = __float2bfloat16((v[i] - mean) * inv * g[c] + b[c]);
  }
}

// ---------- bf16 MFMA GEMM: C[M][N] = A[M][K] @ Bt[N][K]^T + bias ----------
// EPI 0: QKV scatter (q scaled 0.125, v transposed)
// EPI 1: outf = addsrc + bias + C
// EPI 2: outb = bf16(gelu_exact(C + bias))
// EPI 3: split-K over blockIdx.z: z==0 -> outf = addsrc + bias + C0;
//        z==1 -> po = bf16(C1)  (combined later by addp_kernel)
template <int EPI>
__global__ __launch_bounds__(256)
void gemm_kernel(const __hip_bfloat16* __restrict__ A,
                 const __hip_bfloat16* __restrict__ Bt,
                 int N, int K, int Ksub,
                 const float* __restrict__ bias,
                 const float* __restrict__ addsrc,
                 float* __restrict__ outf,
                 __hip_bfloat16* __restrict__ outb,
                 __hip_bfloat16* __restrict__ qo,
                 __hip_bfloat16* __restrict__ ko,
                 __hip_bfloat16* __restrict__ vo,
                 __hip_bfloat16* __restrict__ po) {
  __shared__ __align__(16) __hip_bfloat16 As[2][128 * 32];
  __shared__ __align__(16) __hip_bfloat16 Bs[2][128 * 32];
  const int t = threadIdx.x;
  const int lane = t & 63, w = t >> 6, quad = lane >> 4, l16 = lane & 15;
  const int bn = blockIdx.x, bm = blockIdx.y, bz = blockIdx.z;
  const int wm = (w & 1) * 64, wn = (w >> 1) * 64;
  const __hip_bfloat16* Abase = A + (size_t)bm * 128 * K;
  const __hip_bfloat16* Bbase = Bt + (size_t)bn * 128 * K;
  const int kBeg = bz * Ksub, kEnd = kBeg + Ksub;

  // stage one 128x32 A-tile + B-tile into buffer b at k-offset k0.
  // LDS dest is linear (global_load_lds constraint); swizzle the GLOBAL
  // source chunk: physical slot p holds logical chunk g = (p - (row>>1)) & 3.
  auto stage = [&](int b, int k0) {
#pragma unroll
    for (int j = 0; j < 2; ++j) {
      int c = j * 256 + t;
      int row = c >> 2;
      int p = c & 3;
      int g = (p - (row >> 1)) & 3;
      async_ld16(Abase + (size_t)row * K + k0 + g * 8, &As[b][c * 8]);
      async_ld16(Bbase + (size_t)row * K + k0 + g * 8, &Bs[b][c * 8]);
    }
  };

  f32x4 acc[4][4] = {};
  stage(0, kBeg);
  int buf = 0;
  for (int k0 = kBeg; k0 < kEnd; k0 += 32, buf ^= 1) {
    __syncthreads();  // compiler emits vmcnt(0) drain: buf's loads complete
    if (k0 + 32 < kEnd) stage(buf ^ 1, k0 + 32);
    bf16x8 af[4], bfv[4];
#pragma unroll
    for (int i = 0; i < 4; ++i) {
      int row = wm + i * 16 + l16;
      int p = (quad + (row >> 1)) & 3;
      af[i] = *(const bf16x8*)(&As[buf][row * 32 + p * 8]);
    }
#pragma unroll
    for (int i = 0; i < 4; ++i) {
      int row = wn + i * 16 + l16;
      int p = (quad + (row >> 1)) & 3;
      bfv[i] = *(const bf16x8*)(&Bs[buf][row * 32 + p * 8]);
    }
#pragma unroll
    for (int mt = 0; mt < 4; ++mt)
#pragma unroll
      for (int nt = 0; nt < 4; ++nt)
        acc[mt][nt] = __builtin_amdgcn_mfma_f32_16x16x32_bf16(af[mt], bfv[nt], acc[mt][nt], 0, 0, 0);
  }
#pragma unroll
  for (int mt = 0; mt < 4; ++mt) {
#pragma unroll
    for (int nt = 0; nt < 4; ++nt) {
      const int n = bn * 128 + wn + nt * 16 + l16;
      const float bz2 = bias[n];
#pragma unroll
      for (int r = 0; r < 4; ++r) {
        const int m = bm * 128 + wm + mt * 16 + quad * 4 + r;
        float val = acc[mt][nt][r];
        if constexpr (EPI == 0) {
          val += bz2;
          int which = n >> 11, d2 = n & 2047;
          int hh = d2 >> 6, hd = d2 & 63;
          if (which == 0)
            qo[((size_t)hh * Sq + m) * HDm + hd] = __float2bfloat16(val * 0.125f);
          else if (which == 1)
            ko[((size_t)hh * Sq + m) * HDm + hd] = __float2bfloat16(val);
          else
            vo[((size_t)hh * HDm + hd) * Sq + m] = __float2bfloat16(val);
        } else if constexpr (EPI == 1) {
          outf[(size_t)m * N + n] = addsrc[(size_t)m * N + n] + bz2 + val;
        } else if constexpr (EPI == 2) {
          val += bz2;
          float gg = 0.5f * val * (1.0f + erff(val * 0.70710678118654752f));
          outb[(size_t)m * N + n] = __float2bfloat16(gg);
        } else {
          if (bz == 0)
            outf[(size_t)m * N + n] = addsrc[(size_t)m * N + n] + bz2 + val;
          else
            po[(size_t)m * N + n] = __float2bfloat16(val);
        }
      }
    }
  }
}

// ---------- out[i] += (float)p[i], vectorized x4 ----------
__global__ __launch_bounds__(256)
void addp_kernel(float* __restrict__ out, const __hip_bfloat16* __restrict__ p) {
  const int i = (blockIdx.x * 256 + threadIdx.x) * 4;
  float4 o = *(const float4*)(out + i);
  const __hip_bfloat16* pp = p + i;
  o.x += (float)pp[0]; o.y += (float)pp[1]; o.z += (float)pp[2]; o.w += (float)pp[3];
  *(float4*)(out + i) = o;
}

// ---------- flash attention: q[h][s][d] (pre-scaled), k[h][s][d], vt[h][d][s] ----------
__global__ __launch_bounds__(256)
void attn_kernel(const __hip_bfloat16* __restrict__ qb,
                 const __hip_bfloat16* __restrict__ kb,
                 const __hip_bfloat16* __restrict__ vt,
                 const float* __restrict__ alibi,
                 __hip_bfloat16* __restrict__ ctx) {
  __shared__ __align__(16) __hip_bfloat16 Kl[64 * 64];
  __shared__ __align__(16) __hip_bfloat16 Vl[64 * 64];     // [d][key]
  __shared__ __align__(16) __hip_bfloat16 Pl[4][16 * 64];  // per-wave P tile
  const int qblk = blockIdx.x, h = blockIdx.y;
  const int t = threadIdx.x, w = t >> 6, lane = t & 63, quad = lane >> 4, l16 = lane & 15;
  const __hip_bfloat16* qh = qb + (size_t)h * Sq * HDm;
  const __hip_bfloat16* kh = kb + (size_t)h * Sq * HDm;
  const __hip_bfloat16* vh = vt + (size_t)h * HDm * Sq;
  const float* al = alibi + (size_t)h * Sq;
  const int qr0 = qblk * 64 + w * 16;
  const bf16x8 qa0 = *(const bf16x8*)(qh + (size_t)(qr0 + l16) * HDm + quad * 8);
  const bf16x8 qa1 = *(const bf16x8*)(qh + (size_t)(qr0 + l16) * HDm + 32 + quad * 8);
  f32x4 o[4] = {};
  float m_i[4], l_i[4];
#pragma unroll
  for (int r = 0; r < 4; ++r) { m_i[r] = -3e38f; l_i[r] = 0.f; }
  for (int kbk = 0; kbk <= qblk; ++kbk) {
    __syncthreads();
#pragma unroll
    for (int j = 0; j < 2; ++j) {
      int c = j * 256 + t;
      int row = c >> 3;
      int swz = (c & 7) ^ (row & 7);
      async_ld16(kh + (size_t)(kbk * 64 + row) * HDm + swz * 8, Kl + c * 8);
      async_ld16(vh + (size_t)row * Sq + kbk * 64 + swz * 8, Vl + c * 8);
    }
    __syncthreads();
    f32x4 sf[4];
    const f32x4 zero = {};
#pragma unroll
    for (int nt = 0; nt < 4; ++nt) {
      int row = nt * 16 + l16;
      bf16x8 kf0 = *(const bf16x8*)(Kl + row * 64 + ((quad ^ (row & 7)) << 3));
      bf16x8 kf1 = *(const bf16x8*)(Kl + row * 64 + (((4 + quad) ^ (row & 7)) << 3));
      sf[nt] = __builtin_amdgcn_mfma_f32_16x16x32_bf16(qa0, kf0, zero, 0, 0, 0);
      sf[nt] = __builtin_amdgcn_mfma_f32_16x16x32_bf16(qa1, kf1, sf[nt], 0, 0, 0);
    }
    const bool diag = (kbk == qblk);
    float mrow[4] = {-3e38f, -3e38f, -3e38f, -3e38f};
#pragma unroll
    for (int nt = 0; nt < 4; ++nt) {
      const float ab = al[kbk * 64 + nt * 16 + l16] * 0.125f;
      const int kcol = nt * 16 + l16;
#pragma unroll
      for (int r = 0; r < 4; ++r) {
        float vv = sf[nt][r] + ab;
        if (diag && kcol > w * 16 + quad * 4 + r) vv = -3e38f;
        sf[nt][r] = vv;
        mrow[r] = fmaxf(mrow[r], vv);
      }
    }
#pragma unroll
    for (int off = 8; off > 0; off >>= 1)
#pragma unroll
      for (int r = 0; r < 4; ++r)
        mrow[r] = fmaxf(mrow[r], __shfl_xor(mrow[r], off, 64));
    float alpha[4], rs[4], p[4][4];
#pragma unroll
    for (int r = 0; r < 4; ++r) {
      float mn = fmaxf(m_i[r], mrow[r]);
      alpha[r] = __expf(m_i[r] - mn);
      m_i[r] = mn;
    }
#pragma unroll
    for (int nt = 0; nt < 4; ++nt)
#pragma unroll
      for (int r = 0; r < 4; ++r) p[nt][r] = __expf(sf[nt][r] - m_i[r]);
#pragma unroll
    for (int r = 0; r < 4; ++r) rs[r] = p[0][r] + p[1][r] + p[2][r] + p[3][r];
#pragma unroll
    for (int off = 8; off > 0; off >>= 1)
#pragma unroll
      for (int r = 0; r < 4; ++r) rs[r] += __shfl_xor(rs[r], off, 64);
#pragma unroll
    for (int r = 0; r < 4; ++r) l_i[r] = l_i[r] * alpha[r] + rs[r];
#pragma unroll
    for (int dt = 0; dt < 4; ++dt)
#pragma unroll
      for (int r = 0; r < 4; ++r) o[dt][r] *= alpha[r];
    __hip_bfloat16* pw = &Pl[w][0];
#pragma unroll
    for (int nt = 0; nt < 4; ++nt)
#pragma unroll
      for (int r = 0; r < 4; ++r) {
        int prow = quad * 4 + r;
        int e = nt * 16 + l16;
        int c16 = e >> 3;
        pw[prow * 64 + ((c16 ^ (prow & 7)) << 3) + (e & 7)] = __float2bfloat16(p[nt][r]);
      }
    asm volatile("s_waitcnt lgkmcnt(0)" ::: "memory");
    const bf16x8 pa0 = *(const bf16x8*)(pw + l16 * 64 + ((quad ^ (l16 & 7)) << 3));
    const bf16x8 pa1 = *(const bf16x8*)(pw + l16 * 64 + (((4 + quad) ^ (l16 & 7)) << 3));
#pragma unroll
    for (int dt = 0; dt < 4; ++dt) {
      int row = dt * 16 + l16;
      bf16x8 v0 = *(const bf16x8*)(Vl + row * 64 + ((quad ^ (row & 7)) << 3));
      bf16x8 v1 = *(const bf16x8*)(Vl + row * 64 + (((4 + quad) ^ (row & 7)) << 3));
      o[dt] = __builtin_amdgcn_mfma_f32_16x16x32_bf16(pa0, v0, o[dt], 0, 0, 0);
      o[dt] = __builtin_amdgcn_mfma_f32_16x16x32_bf16(pa1, v1, o[dt], 0, 0, 0);
    }
  }
#pragma unroll
  for (int dt = 0; dt < 4; ++dt)
#pragma unroll
    for (int r = 0; r < 4; ++r) {
      int srow = qblk * 64 + w * 16 + quad * 4 + r;
      ctx[(size_t)srow * Dm + h * HDm + dt * 16 + l16] =
          __float2bfloat16(o[dt][r] / l_i[r]);
    }
}

extern "C" void kernel_launch(void* const* d_in, const int* in_sizes, int n_in,
                              void* d_out, int out_size, void* d_ws, size_t ws_size,
                              hipStream_t stream) {
  const float* x     = (const float*)d_in[0];
  const float* alibi = (const float*)d_in[1];
  const float* ln1g  = (const float*)d_in[3];
  const float* ln1b  = (const float*)d_in[4];
  const float* ln2g  = (const float*)d_in[5];
  const float* ln2b  = (const float*)d_in[6];
  const float* wqkv  = (const float*)d_in[7];
  const float* bqkv  = (const float*)d_in[8];
  const float* wo    = (const float*)d_in[9];
  const float* bo    = (const float*)d_in[10];
  const float* w1    = (const float*)d_in[11];
  const float* b1    = (const float*)d_in[12];
  const float* w2    = (const float*)d_in[13];
  const float* b2    = (const float*)d_in[14];
  float* out = (float*)d_out;

  // ---- workspace with lifetime-based aliasing; peak ~92 MB ----
  char* p = (char*)d_ws;
  auto alloc = [&](size_t bytes) {
    char* r = p;
    p += (bytes + 255) & ~(size_t)255;
    return r;
  };
  constexpr size_t SD2 = (size_t)Sq * Dm * 2;
  char* R2 = alloc((size_t)FFm * Dm * 2);
  char* R1 = alloc(4 * SD2);
  __hip_bfloat16* hb   = (__hip_bfloat16*)alloc(SD2);
  float*          resb = (float*)alloc((size_t)Sq * Dm * 4);

  __hip_bfloat16* wqkvT = (__hip_bfloat16*)R2;
  __hip_bfloat16* w1T   = (__hip_bfloat16*)R2;
  __hip_bfloat16* w2T   = (__hip_bfloat16*)R2;
  __hip_bfloat16* qbuf  = (__hip_bfloat16*)(R1 + 0 * SD2);
  __hip_bfloat16* kbuf  = (__hip_bfloat16*)(R1 + 1 * SD2);
  __hip_bfloat16* vtbuf = (__hip_bfloat16*)(R1 + 2 * SD2);
  __hip_bfloat16* ctxb  = (__hip_bfloat16*)(R1 + 3 * SD2);
  __hip_bfloat16* woT   = (__hip_bfloat16*)(R1 + 0 * SD2);  // after attn
  __hip_bfloat16* t1b   = (__hip_bfloat16*)R1;              // after proj
  __hip_bfloat16* part  = hb;                               // mlp-down z=1 partial (hb dead)

  // 1) wqkv transpose+cast, ln1
  tcast_kernel<<<dim3(3 * Dm / 64, Dm / 64), 256, 0, stream>>>(wqkv, wqkvT, Dm, 3 * Dm);
  ln_kernel<<<Sq, 256, 0, stream>>>(x, ln1g, ln1b, hb);
  // 2) QKV gemm
  gemm_kernel<0><<<dim3(3 * Dm / 128, Sq / 128), 256, 0, stream>>>(
      hb, wqkvT, 3 * Dm, Dm, Dm, bqkv, nullptr, nullptr, nullptr, qbuf, kbuf, vtbuf, nullptr);
  // 3) w1 transpose
  tcast_kernel<<<dim3(FFm / 64, Dm / 64), 256, 0, stream>>>(w1, w1T, Dm, FFm);
  // 4) flash attention
  attn_kernel<<<dim3(Sq / 64, NH), 256, 0, stream>>>(qbuf, kbuf, vtbuf, alibi, ctxb);
  // 5) wo transpose into q slot
  tcast_kernel<<<dim3(Dm / 64, Dm / 64), 256, 0, stream>>>(wo, woT, Dm, Dm);
  // 6) attn proj + residual -> resb (fp32)
  gemm_kernel<1><<<dim3(Dm / 128, Sq / 128), 256, 0, stream>>>(
      ctxb, woT, Dm, Dm, Dm, bo, x, resb, nullptr, nullptr, nullptr, nullptr, nullptr);
  // 7) ln2
  ln_kernel<<<Sq, 256, 0, stream>>>(resb, ln2g, ln2b, hb);
  // 8) mlp up + gelu -> t1b
  gemm_kernel<2><<<dim3(FFm / 128, Sq / 128), 256, 0, stream>>>(
      hb, w1T, FFm, Dm, Dm, b1, nullptr, nullptr, t1b, nullptr, nullptr, nullptr, nullptr);
  // 9) w2 transpose
  tcast_kernel<<<dim3(Dm / 64, FFm / 64), 256, 0, stream>>>(w2, w2T, FFm, Dm);
  // 10) mlp down, split-K=2: z=0 -> out = resb + b2 + C0 ; z=1 -> part
  gemm_kernel<3><<<dim3(Dm / 128, Sq / 128, 2), 256, 0, stream>>>(
      t1b, w2T, Dm, FFm, FFm / 2, b2, resb, out, nullptr, nullptr, nullptr, nullptr, part);
  // 11) out += part
  addp_kernel<<<(Sq * Dm) / 1024, 256, 0, stream>>>(out, part);
}

// Round 4
// 674.605 us; speedup vs baseline: 1.1756x; 1.0606x over previous
//
#include <hip/hip_runtime.h>
#include <hip/hip_bf16.h>
#include <cstdint>
#include <cstddef>

static constexpr int Sq  = 2048;
static constexpr int Dm  = 2048;
static constexpr int NH  = 32;
static constexpr int HDm = 64;
static constexpr int FFm = 8192;

typedef __bf16 bf16x8 __attribute__((ext_vector_type(8)));
typedef float  f32x4  __attribute__((ext_vector_type(4)));

__device__ __forceinline__ void async_ld16(const void* g, void* l) {
  __builtin_amdgcn_global_load_lds((const __attribute__((address_space(1))) void*)g,
                                   (__attribute__((address_space(3))) void*)l, 16, 0, 0);
}

// ---------- transpose + cast: in[K][N] f32 -> out[N][K] bf16 ----------
__global__ __launch_bounds__(256)
void tcast_kernel(const float* __restrict__ in, __hip_bfloat16* __restrict__ out,
                  int K, int N) {
  __shared__ float tile[64][65];
  const int tc = blockIdx.x * 64;
  const int tr = blockIdx.y * 64;
  const int cx = threadIdx.x & 63;
  const int ry = threadIdx.x >> 6;
#pragma unroll
  for (int i = 0; i < 16; ++i) {
    int r = ry + i * 4;
    tile[r][cx] = in[(size_t)(tr + r) * N + tc + cx];
  }
  __syncthreads();
#pragma unroll
  for (int i = 0; i < 16; ++i) {
    int r = ry + i * 4;
    out[(size_t)(tc + r) * K + tr + cx] = __float2bfloat16(tile[cx][r]);
  }
}

// ---------- layernorm row kernel: x f32 -> out bf16 ----------
__global__ __launch_bounds__(256)
void ln_kernel(const float* __restrict__ x, const float* __restrict__ g,
               const float* __restrict__ b, __hip_bfloat16* __restrict__ out) {
  __shared__ float red[4];
  const int t = threadIdx.x;
  const float* xr = x + (size_t)blockIdx.x * Dm;
  float v[8];
  float s = 0.f;
#pragma unroll
  for (int i = 0; i < 8; ++i) { v[i] = xr[t + i * 256]; s += v[i]; }
#pragma unroll
  for (int off = 32; off > 0; off >>= 1) s += __shfl_down(s, off, 64);
  if ((t & 63) == 0) red[t >> 6] = s;
  __syncthreads();
  const float mean = (red[0] + red[1] + red[2] + red[3]) * (1.f / Dm);
  __syncthreads();
  float vs = 0.f;
#pragma unroll
  for (int i = 0; i < 8; ++i) { float d = v[i] - mean; vs += d * d; }
#pragma unroll
  for (int off = 32; off > 0; off >>= 1) vs += __shfl_down(vs, off, 64);
  if ((t & 63) == 0) red[t >> 6] = vs;
  __syncthreads();
  const float inv = rsqrtf((red[0] + red[1] + red[2] + red[3]) * (1.f / Dm) + 1e-5f);
  __hip_bfloat16* orow = out + (size_t)blockIdx.x * Dm;
#pragma unroll
  for (int i = 0; i < 8; ++i) {
    int c = t + i * 256;
    orow[c] = __float2bfloat16((v[i] - mean) * inv * g[c] + b[c]);
  }
}

// ---------- bf16 MFMA GEMM: C[M][N] = A[M][K] @ Bt[N][K]^T + bias ----------
// EPI 0: QKV scatter (q scaled 0.125, v transposed)
// EPI 1: outf = addsrc + bias + C
// EPI 2: outb = bf16(gelu_exact(C + bias))
// EPI 3: split-K over blockIdx.z: z==0 -> outf = addsrc + bias + C0;
//        z==1 -> po = bf16(C1)  (combined later by addp_kernel)
template <int EPI>
__global__ __launch_bounds__(256)
void gemm_kernel(const __hip_bfloat16* __restrict__ A,
                 const __hip_bfloat16* __restrict__ Bt,
                 int N, int K, int Ksub,
                 const float* __restrict__ bias,
                 const float* __restrict__ addsrc,
                 float* __restrict__ outf,
                 __hip_bfloat16* __restrict__ outb,
                 __hip_bfloat16* __restrict__ qo,
                 __hip_bfloat16* __restrict__ ko,
                 __hip_bfloat16* __restrict__ vo,
                 __hip_bfloat16* __restrict__ po) {
  __shared__ __align__(16) __hip_bfloat16 As[2][128 * 32];
  __shared__ __align__(16) __hip_bfloat16 Bs[2][128 * 32];
  const int t = threadIdx.x;
  const int lane = t & 63, w = t >> 6, quad = lane >> 4, l16 = lane & 15;
  const int bn = blockIdx.x, bm = blockIdx.y, bz = blockIdx.z;
  const int wm = (w & 1) * 64, wn = (w >> 1) * 64;
  const __hip_bfloat16* Abase = A + (size_t)bm * 128 * K;
  const __hip_bfloat16* Bbase = Bt + (size_t)bn * 128 * K;
  const int kBeg = bz * Ksub, kEnd = kBeg + Ksub;

  auto stage = [&](int b, int k0) {
#pragma unroll
    for (int j = 0; j < 2; ++j) {
      int c = j * 256 + t;
      int row = c >> 2;
      int p = c & 3;
      int g = (p - (row >> 1)) & 3;
      async_ld16(Abase + (size_t)row * K + k0 + g * 8, &As[b][c * 8]);
      async_ld16(Bbase + (size_t)row * K + k0 + g * 8, &Bs[b][c * 8]);
    }
  };

  f32x4 acc[4][4] = {};
  stage(0, kBeg);
  int buf = 0;
  for (int k0 = kBeg; k0 < kEnd; k0 += 32, buf ^= 1) {
    __syncthreads();
    if (k0 + 32 < kEnd) stage(buf ^ 1, k0 + 32);
    bf16x8 af[4], bfv[4];
#pragma unroll
    for (int i = 0; i < 4; ++i) {
      int row = wm + i * 16 + l16;
      int p = (quad + (row >> 1)) & 3;
      af[i] = *(const bf16x8*)(&As[buf][row * 32 + p * 8]);
    }
#pragma unroll
    for (int i = 0; i < 4; ++i) {
      int row = wn + i * 16 + l16;
      int p = (quad + (row >> 1)) & 3;
      bfv[i] = *(const bf16x8*)(&Bs[buf][row * 32 + p * 8]);
    }
#pragma unroll
    for (int mt = 0; mt < 4; ++mt)
#pragma unroll
      for (int nt = 0; nt < 4; ++nt)
        acc[mt][nt] = __builtin_amdgcn_mfma_f32_16x16x32_bf16(af[mt], bfv[nt], acc[mt][nt], 0, 0, 0);
  }
#pragma unroll
  for (int mt = 0; mt < 4; ++mt) {
#pragma unroll
    for (int nt = 0; nt < 4; ++nt) {
      const int n = bn * 128 + wn + nt * 16 + l16;
      const float bz2 = bias[n];
#pragma unroll
      for (int r = 0; r < 4; ++r) {
        const int m = bm * 128 + wm + mt * 16 + quad * 4 + r;
        float val = acc[mt][nt][r];
        if constexpr (EPI == 0) {
          val += bz2;
          int which = n >> 11, d2 = n & 2047;
          int hh = d2 >> 6, hd = d2 & 63;
          if (which == 0)
            qo[((size_t)hh * Sq + m) * HDm + hd] = __float2bfloat16(val * 0.125f);
          else if (which == 1)
            ko[((size_t)hh * Sq + m) * HDm + hd] = __float2bfloat16(val);
          else
            vo[((size_t)hh * HDm + hd) * Sq + m] = __float2bfloat16(val);
        } else if constexpr (EPI == 1) {
          outf[(size_t)m * N + n] = addsrc[(size_t)m * N + n] + bz2 + val;
        } else if constexpr (EPI == 2) {
          val += bz2;
          float gg = 0.5f * val * (1.0f + erff(val * 0.70710678118654752f));
          outb[(size_t)m * N + n] = __float2bfloat16(gg);
        } else {
          if (bz == 0)
            outf[(size_t)m * N + n] = addsrc[(size_t)m * N + n] + bz2 + val;
          else
            po[(size_t)m * N + n] = __float2bfloat16(val);
        }
      }
    }
  }
}

// ---------- out[i] += (float)p[i], vectorized x4 ----------
__global__ __launch_bounds__(256)
void addp_kernel(float* __restrict__ out, const __hip_bfloat16* __restrict__ p) {
  const int i = (blockIdx.x * 256 + threadIdx.x) * 4;
  float4 o = *(const float4*)(out + i);
  const __hip_bfloat16* pp = p + i;
  o.x += (float)pp[0]; o.y += (float)pp[1]; o.z += (float)pp[2]; o.w += (float)pp[3];
  *(float4*)(out + i) = o;
}

// ---------- flash attention, paired q-tiles (i, 31-i), double-buffered K/V ----
// q[h][s][d] (pre-scaled by 0.125), k[h][s][d], vt[h][d][s]
__global__ __launch_bounds__(256)
void attn_kernel(const __hip_bfloat16* __restrict__ qb,
                 const __hip_bfloat16* __restrict__ kb,
                 const __hip_bfloat16* __restrict__ vt,
                 const float* __restrict__ alibi,
                 __hip_bfloat16* __restrict__ ctx) {
  __shared__ __align__(16) __hip_bfloat16 Kl[2][64 * 64];
  __shared__ __align__(16) __hip_bfloat16 Vl[2][64 * 64];   // [d][key]
  __shared__ __align__(16) __hip_bfloat16 Pl[4][16 * 64];   // per-wave P tile
  const int pi = blockIdx.x, h = blockIdx.y;
  const int qA = pi, qB = (Sq / 64 - 1) - pi;   // 33 steps total, perfectly balanced
  const int t = threadIdx.x, w = t >> 6, lane = t & 63, quad = lane >> 4, l16 = lane & 15;
  const __hip_bfloat16* qh = qb + (size_t)h * Sq * HDm;
  const __hip_bfloat16* kh = kb + (size_t)h * Sq * HDm;
  const __hip_bfloat16* vh = vt + (size_t)h * HDm * Sq;
  const float* al = alibi + (size_t)h * Sq;

  const int rA = qA * 64 + w * 16 + l16;
  const int rB = qB * 64 + w * 16 + l16;
  const bf16x8 qA0 = *(const bf16x8*)(qh + (size_t)rA * HDm + quad * 8);
  const bf16x8 qA1 = *(const bf16x8*)(qh + (size_t)rA * HDm + 32 + quad * 8);
  const bf16x8 qB0 = *(const bf16x8*)(qh + (size_t)rB * HDm + quad * 8);
  const bf16x8 qB1 = *(const bf16x8*)(qh + (size_t)rB * HDm + 32 + quad * 8);

  auto stageS = [&](int b, int s) {
    const int kbk = (s <= qA) ? s : s - qA - 1;
#pragma unroll
    for (int j = 0; j < 2; ++j) {
      int c = j * 256 + t;
      int row = c >> 3;
      int swz = (c & 7) ^ (row & 7);
      async_ld16(kh + (size_t)(kbk * 64 + row) * HDm + swz * 8, &Kl[b][c * 8]);
      async_ld16(vh + (size_t)row * Sq + kbk * 64 + swz * 8, &Vl[b][c * 8]);
    }
  };

  f32x4 o[4] = {};
  float m_i[4], l_i[4];
#pragma unroll
  for (int r = 0; r < 4; ++r) { m_i[r] = -3e38f; l_i[r] = 0.f; }

  const int total = qA + qB + 2;  // 33
  stageS(0, 0);
  int buf = 0;
  for (int s = 0; s < total; ++s, buf ^= 1) {
    __syncthreads();  // drains buf's loads (issued last iter); guards LDS reuse
    if (s + 1 < total) stageS(buf ^ 1, s + 1);
    const bool ph = (s > qA);
    const int kbk = ph ? s - qA - 1 : s;
    const int qblk = ph ? qB : qA;
    const bf16x8 a0 = ph ? qB0 : qA0;
    const bf16x8 a1 = ph ? qB1 : qA1;

    f32x4 sf[4];
    const f32x4 zero = {};
#pragma unroll
    for (int nt = 0; nt < 4; ++nt) {
      int row = nt * 16 + l16;
      bf16x8 kf0 = *(const bf16x8*)(&Kl[buf][row * 64 + ((quad ^ (row & 7)) << 3)]);
      bf16x8 kf1 = *(const bf16x8*)(&Kl[buf][row * 64 + (((4 + quad) ^ (row & 7)) << 3)]);
      sf[nt] = __builtin_amdgcn_mfma_f32_16x16x32_bf16(a0, kf0, zero, 0, 0, 0);
      sf[nt] = __builtin_amdgcn_mfma_f32_16x16x32_bf16(a1, kf1, sf[nt], 0, 0, 0);
    }
    const bool diag = (kbk == qblk);
    float mrow[4] = {-3e38f, -3e38f, -3e38f, -3e38f};
#pragma unroll
    for (int nt = 0; nt < 4; ++nt) {
      const float ab = al[kbk * 64 + nt * 16 + l16] * 0.125f;
      const int kcol = nt * 16 + l16;
#pragma unroll
      for (int r = 0; r < 4; ++r) {
        float vv = sf[nt][r] + ab;
        if (diag && kcol > w * 16 + quad * 4 + r) vv = -3e38f;
        sf[nt][r] = vv;
        mrow[r] = fmaxf(mrow[r], vv);
      }
    }
#pragma unroll
    for (int off = 8; off > 0; off >>= 1)
#pragma unroll
      for (int r = 0; r < 4; ++r)
        mrow[r] = fmaxf(mrow[r], __shfl_xor(mrow[r], off, 64));
    float alpha[4], rs[4], p[4][4];
#pragma unroll
    for (int r = 0; r < 4; ++r) {
      float mn = fmaxf(m_i[r], mrow[r]);
      alpha[r] = __expf(m_i[r] - mn);
      m_i[r] = mn;
    }
#pragma unroll
    for (int nt = 0; nt < 4; ++nt)
#pragma unroll
      for (int r = 0; r < 4; ++r) p[nt][r] = __expf(sf[nt][r] - m_i[r]);
#pragma unroll
    for (int r = 0; r < 4; ++r) rs[r] = p[0][r] + p[1][r] + p[2][r] + p[3][r];
#pragma unroll
    for (int off = 8; off > 0; off >>= 1)
#pragma unroll
      for (int r = 0; r < 4; ++r) rs[r] += __shfl_xor(rs[r], off, 64);
#pragma unroll
    for (int r = 0; r < 4; ++r) l_i[r] = l_i[r] * alpha[r] + rs[r];
#pragma unroll
    for (int dt = 0; dt < 4; ++dt)
#pragma unroll
      for (int r = 0; r < 4; ++r) o[dt][r] *= alpha[r];
    __hip_bfloat16* pw = &Pl[w][0];
#pragma unroll
    for (int nt = 0; nt < 4; ++nt)
#pragma unroll
      for (int r = 0; r < 4; ++r) {
        int prow = quad * 4 + r;
        int e = nt * 16 + l16;
        int c16 = e >> 3;
        pw[prow * 64 + ((c16 ^ (prow & 7)) << 3) + (e & 7)] = __float2bfloat16(p[nt][r]);
      }
    asm volatile("s_waitcnt lgkmcnt(0)" ::: "memory");
    const bf16x8 pa0 = *(const bf16x8*)(pw + l16 * 64 + ((quad ^ (l16 & 7)) << 3));
    const bf16x8 pa1 = *(const bf16x8*)(pw + l16 * 64 + (((4 + quad) ^ (l16 & 7)) << 3));
#pragma unroll
    for (int dt = 0; dt < 4; ++dt) {
      int row = dt * 16 + l16;
      bf16x8 v0 = *(const bf16x8*)(&Vl[buf][row * 64 + ((quad ^ (row & 7)) << 3)]);
      bf16x8 v1 = *(const bf16x8*)(&Vl[buf][row * 64 + (((4 + quad) ^ (row & 7)) << 3)]);
      o[dt] = __builtin_amdgcn_mfma_f32_16x16x32_bf16(pa0, v0, o[dt], 0, 0, 0);
      o[dt] = __builtin_amdgcn_mfma_f32_16x16x32_bf16(pa1, v1, o[dt], 0, 0, 0);
    }
    if (s == qA) {  // phase A done: store and reset online-softmax state
#pragma unroll
      for (int dt = 0; dt < 4; ++dt)
#pragma unroll
        for (int r = 0; r < 4; ++r) {
          int srow = qA * 64 + w * 16 + quad * 4 + r;
          ctx[(size_t)srow * Dm + h * HDm + dt * 16 + l16] =
              __float2bfloat16(o[dt][r] / l_i[r]);
          o[dt][r] = 0.f;
        }
#pragma unroll
      for (int r = 0; r < 4; ++r) { m_i[r] = -3e38f; l_i[r] = 0.f; }
    }
  }
#pragma unroll
  for (int dt = 0; dt < 4; ++dt)
#pragma unroll
    for (int r = 0; r < 4; ++r) {
      int srow = qB * 64 + w * 16 + quad * 4 + r;
      ctx[(size_t)srow * Dm + h * HDm + dt * 16 + l16] =
          __float2bfloat16(o[dt][r] / l_i[r]);
    }
}

extern "C" void kernel_launch(void* const* d_in, const int* in_sizes, int n_in,
                              void* d_out, int out_size, void* d_ws, size_t ws_size,
                              hipStream_t stream) {
  const float* x     = (const float*)d_in[0];
  const float* alibi = (const float*)d_in[1];
  const float* ln1g  = (const float*)d_in[3];
  const float* ln1b  = (const float*)d_in[4];
  const float* ln2g  = (const float*)d_in[5];
  const float* ln2b  = (const float*)d_in[6];
  const float* wqkv  = (const float*)d_in[7];
  const float* bqkv  = (const float*)d_in[8];
  const float* wo    = (const float*)d_in[9];
  const float* bo    = (const float*)d_in[10];
  const float* w1    = (const float*)d_in[11];
  const float* b1    = (const float*)d_in[12];
  const float* w2    = (const float*)d_in[13];
  const float* b2    = (const float*)d_in[14];
  float* out = (float*)d_out;

  char* p = (char*)d_ws;
  auto alloc = [&](size_t bytes) {
    char* r = p;
    p += (bytes + 255) & ~(size_t)255;
    return r;
  };
  constexpr size_t SD2 = (size_t)Sq * Dm * 2;
  char* R2 = alloc((size_t)FFm * Dm * 2);
  char* R1 = alloc(4 * SD2);
  __hip_bfloat16* hb   = (__hip_bfloat16*)alloc(SD2);
  float*          resb = (float*)alloc((size_t)Sq * Dm * 4);

  __hip_bfloat16* wqkvT = (__hip_bfloat16*)R2;
  __hip_bfloat16* w1T   = (__hip_bfloat16*)R2;
  __hip_bfloat16* w2T   = (__hip_bfloat16*)R2;
  __hip_bfloat16* qbuf  = (__hip_bfloat16*)(R1 + 0 * SD2);
  __hip_bfloat16* kbuf  = (__hip_bfloat16*)(R1 + 1 * SD2);
  __hip_bfloat16* vtbuf = (__hip_bfloat16*)(R1 + 2 * SD2);
  __hip_bfloat16* ctxb  = (__hip_bfloat16*)(R1 + 3 * SD2);
  __hip_bfloat16* woT   = (__hip_bfloat16*)(R1 + 0 * SD2);  // after attn
  __hip_bfloat16* t1b   = (__hip_bfloat16*)R1;              // after proj
  __hip_bfloat16* part  = hb;                               // split-K partials (hb dead windows)

  // 1) wqkv transpose+cast, ln1
  tcast_kernel<<<dim3(3 * Dm / 64, Dm / 64), 256, 0, stream>>>(wqkv, wqkvT, Dm, 3 * Dm);
  ln_kernel<<<Sq, 256, 0, stream>>>(x, ln1g, ln1b, hb);
  // 2) QKV gemm
  gemm_kernel<0><<<dim3(3 * Dm / 128, Sq / 128), 256, 0, stream>>>(
      hb, wqkvT, 3 * Dm, Dm, Dm, bqkv, nullptr, nullptr, nullptr, qbuf, kbuf, vtbuf, nullptr);
  // 3) w1 transpose
  tcast_kernel<<<dim3(FFm / 64, Dm / 64), 256, 0, stream>>>(w1, w1T, Dm, FFm);
  // 4) flash attention (paired q-tiles, balanced)
  attn_kernel<<<dim3(Sq / 128, NH), 256, 0, stream>>>(qbuf, kbuf, vtbuf, alibi, ctxb);
  // 5) wo transpose into q slot
  tcast_kernel<<<dim3(Dm / 64, Dm / 64), 256, 0, stream>>>(wo, woT, Dm, Dm);
  // 6) attn proj + residual -> resb (fp32), split-K=2
  gemm_kernel<3><<<dim3(Dm / 128, Sq / 128, 2), 256, 0, stream>>>(
      ctxb, woT, Dm, Dm, Dm / 2, bo, x, resb, nullptr, nullptr, nullptr, nullptr, part);
  addp_kernel<<<(Sq * Dm) / 1024, 256, 0, stream>>>(resb, part);
  // 7) ln2
  ln_kernel<<<Sq, 256, 0, stream>>>(resb, ln2g, ln2b, hb);
  // 8) mlp up + gelu -> t1b
  gemm_kernel<2><<<dim3(FFm / 128, Sq / 128), 256, 0, stream>>>(
      hb, w1T, FFm, Dm, Dm, b1, nullptr, nullptr, t1b, nullptr, nullptr, nullptr, nullptr);
  // 9) w2 transpose
  tcast_kernel<<<dim3(Dm / 64, FFm / 64), 256, 0, stream>>>(w2, w2T, FFm, Dm);
  // 10) mlp down, split-K=2: z=0 -> out = resb + b2 + C0 ; z=1 -> part
  gemm_kernel<3><<<dim3(Dm / 128, Sq / 128, 2), 256, 0, stream>>>(
      t1b, w2T, Dm, FFm, FFm / 2, b2, resb, out, nullptr, nullptr, nullptr, nullptr, part);
  // 11) out += part
  addp_kernel<<<(Sq * Dm) / 1024, 256, 0, stream>>>(out, part);
}

// Round 5
// 652.637 us; speedup vs baseline: 1.2152x; 1.0337x over previous
//
#include <hip/hip_runtime.h>
#include <hip/hip_bf16.h>
#include <cstdint>
#include <cstddef>

static constexpr int Sq  = 2048;
static constexpr int Dm  = 2048;
static constexpr int NH  = 32;
static constexpr int HDm = 64;
static constexpr int FFm = 8192;

typedef __bf16 bf16x8 __attribute__((ext_vector_type(8)));
typedef float  f32x4  __attribute__((ext_vector_type(4)));

__device__ __forceinline__ void async_ld16(const void* g, void* l) {
  __builtin_amdgcn_global_load_lds((const __attribute__((address_space(1))) void*)g,
                                   (__attribute__((address_space(3))) void*)l, 16, 0, 0);
}

// ---------- transpose + cast: in[K][N] f32 -> out[N][K] bf16 ----------
__global__ __launch_bounds__(256)
void tcast_kernel(const float* __restrict__ in, __hip_bfloat16* __restrict__ out,
                  int K, int N) {
  __shared__ float tile[64][65];
  const int tc = blockIdx.x * 64;
  const int tr = blockIdx.y * 64;
  const int cx = threadIdx.x & 63;
  const int ry = threadIdx.x >> 6;
#pragma unroll
  for (int i = 0; i < 16; ++i) {
    int r = ry + i * 4;
    tile[r][cx] = in[(size_t)(tr + r) * N + tc + cx];
  }
  __syncthreads();
#pragma unroll
  for (int i = 0; i < 16; ++i) {
    int r = ry + i * 4;
    out[(size_t)(tc + r) * K + tr + cx] = __float2bfloat16(tile[cx][r]);
  }
}

// ---------- layernorm row kernel: x f32 -> out bf16 ----------
__global__ __launch_bounds__(256)
void ln_kernel(const float* __restrict__ x, const float* __restrict__ g,
               const float* __restrict__ b, __hip_bfloat16* __restrict__ out) {
  __shared__ float red[4];
  const int t = threadIdx.x;
  const float* xr = x + (size_t)blockIdx.x * Dm;
  float v[8];
  float s = 0.f;
#pragma unroll
  for (int i = 0; i < 8; ++i) { v[i] = xr[t + i * 256]; s += v[i]; }
#pragma unroll
  for (int off = 32; off > 0; off >>= 1) s += __shfl_down(s, off, 64);
  if ((t & 63) == 0) red[t >> 6] = s;
  __syncthreads();
  const float mean = (red[0] + red[1] + red[2] + red[3]) * (1.f / Dm);
  __syncthreads();
  float vs = 0.f;
#pragma unroll
  for (int i = 0; i < 8; ++i) { float d = v[i] - mean; vs += d * d; }
#pragma unroll
  for (int off = 32; off > 0; off >>= 1) vs += __shfl_down(vs, off, 64);
  if ((t & 63) == 0) red[t >> 6] = vs;
  __syncthreads();
  const float inv = rsqrtf((red[0] + red[1] + red[2] + red[3]) * (1.f / Dm) + 1e-5f);
  __hip_bfloat16* orow = out + (size_t)blockIdx.x * Dm;
#pragma unroll
  for (int i = 0; i < 8; ++i) {
    int c = t + i * 256;
    orow[c] = __float2bfloat16((v[i] - mean) * inv * g[c] + b[c]);
  }
}

// ---------- bf16 MFMA GEMM, register-staged pipelined K-loop ----------
// C[M][N] = A[M][K] @ Bt[N][K]^T (+bias, epilogues as before).
// Pipeline: global->VGPR prefetch (distance 2) -> ds_write -> raw s_barrier
// (lgkmcnt only; vmem loads stay in flight across barriers).
// Requires gridDim.y == 16 (M=2048, 128-tile) for the XCD swizzle decode.
template <int EPI>
__global__ __launch_bounds__(256)
void gemm_kernel(const __hip_bfloat16* __restrict__ A,
                 const __hip_bfloat16* __restrict__ Bt,
                 int N, int K, int Ksub,
                 const float* __restrict__ bias,
                 const float* __restrict__ addsrc,
                 float* __restrict__ outf,
                 __hip_bfloat16* __restrict__ outb,
                 __hip_bfloat16* __restrict__ qo,
                 __hip_bfloat16* __restrict__ ko,
                 __hip_bfloat16* __restrict__ vo,
                 __hip_bfloat16* __restrict__ po) {
  __shared__ __align__(16) __hip_bfloat16 As[2][128 * 32];
  __shared__ __align__(16) __hip_bfloat16 Bs[2][128 * 32];
  const int t = threadIdx.x;
  const int lane = t & 63, w = t >> 6, quad = lane >> 4, l16 = lane & 15;
  // XCD swizzle: contiguous bn span per XCD for B-tile L2 locality.
  const int nbx = gridDim.x;
  const int id = blockIdx.y * nbx + blockIdx.x;
  const int chunk = (nbx * 16) >> 3;
  const int nid = (id & 7) * chunk + (id >> 3);
  const int bn = nid >> 4, bm = nid & 15;
  const int bz = blockIdx.z;
  const int wm = (w & 1) * 64, wn = (w >> 1) * 64;
  const __hip_bfloat16* Abase = A + (size_t)bm * 128 * K;
  const __hip_bfloat16* Bbase = Bt + (size_t)bn * 128 * K;
  const int kBeg = bz * Ksub;
  const int kSteps = Ksub / 32;  // even, >= 32 for all our shapes

  // per-thread staging geometry: two 16B chunks per tile (c0, c1)
  const int c0 = t, c1 = t + 256;
  const int r0 = c0 >> 2, g0 = ((c0 & 3) - (r0 >> 1)) & 3;
  const int r1 = c1 >> 2, g1 = ((c1 & 3) - (r1 >> 1)) & 3;
  const __hip_bfloat16* a0p = Abase + (size_t)r0 * K + g0 * 8;
  const __hip_bfloat16* a1p = Abase + (size_t)r1 * K + g1 * 8;
  const __hip_bfloat16* b0p = Bbase + (size_t)r0 * K + g0 * 8;
  const __hip_bfloat16* b1p = Bbase + (size_t)r1 * K + g1 * 8;

  struct Stage { bf16x8 a0, a1, b0, b1; };
  auto gload = [&](int k0) {
    Stage s;
    s.a0 = *(const bf16x8*)(a0p + k0);
    s.a1 = *(const bf16x8*)(a1p + k0);
    s.b0 = *(const bf16x8*)(b0p + k0);
    s.b1 = *(const bf16x8*)(b1p + k0);
    return s;
  };
  auto swrite = [&](int b, const Stage& s) {
    *(bf16x8*)(&As[b][c0 * 8]) = s.a0;
    *(bf16x8*)(&As[b][c1 * 8]) = s.a1;
    *(bf16x8*)(&Bs[b][c0 * 8]) = s.b0;
    *(bf16x8*)(&Bs[b][c1 * 8]) = s.b1;
  };

  f32x4 acc[4][4] = {};
  auto compute = [&](int b) {
    bf16x8 af[4], bfv[4];
#pragma unroll
    for (int i = 0; i < 4; ++i) {
      int row = wm + i * 16 + l16;
      int p = (quad + (row >> 1)) & 3;
      af[i] = *(const bf16x8*)(&As[b][row * 32 + p * 8]);
    }
#pragma unroll
    for (int i = 0; i < 4; ++i) {
      int row = wn + i * 16 + l16;
      int p = (quad + (row >> 1)) & 3;
      bfv[i] = *(const bf16x8*)(&Bs[b][row * 32 + p * 8]);
    }
#pragma unroll
    for (int mt = 0; mt < 4; ++mt)
#pragma unroll
      for (int nt = 0; nt < 4; ++nt)
        acc[mt][nt] = __builtin_amdgcn_mfma_f32_16x16x32_bf16(af[mt], bfv[nt], acc[mt][nt], 0, 0, 0);
  };

#define BAR() asm volatile("s_waitcnt lgkmcnt(0)\ns_barrier" ::: "memory")
  Stage s0 = gload(kBeg);
  Stage s1 = gload(kBeg + 32);
  swrite(0, s0);
  BAR();
  for (int i = 0; i < kSteps; i += 2) {
    if (i + 2 < kSteps) s0 = gload(kBeg + (i + 2) * 32);
    compute(0);
    swrite(1, s1);
    BAR();
    if (i + 3 < kSteps) s1 = gload(kBeg + (i + 3) * 32);
    compute(1);
    if (i + 2 < kSteps) swrite(0, s0);
    BAR();
  }
#undef BAR

#pragma unroll
  for (int mt = 0; mt < 4; ++mt) {
#pragma unroll
    for (int nt = 0; nt < 4; ++nt) {
      const int n = bn * 128 + wn + nt * 16 + l16;
      const float bz2 = bias[n];
#pragma unroll
      for (int r = 0; r < 4; ++r) {
        const int m = bm * 128 + wm + mt * 16 + quad * 4 + r;
        float val = acc[mt][nt][r];
        if constexpr (EPI == 0) {
          val += bz2;
          int which = n >> 11, d2 = n & 2047;
          int hh = d2 >> 6, hd = d2 & 63;
          if (which == 0)
            qo[((size_t)hh * Sq + m) * HDm + hd] = __float2bfloat16(val * 0.125f);
          else if (which == 1)
            ko[((size_t)hh * Sq + m) * HDm + hd] = __float2bfloat16(val);
          else
            vo[((size_t)hh * HDm + hd) * Sq + m] = __float2bfloat16(val);
        } else if constexpr (EPI == 1) {
          outf[(size_t)m * N + n] = addsrc[(size_t)m * N + n] + bz2 + val;
        } else if constexpr (EPI == 2) {
          val += bz2;
          float gg = 0.5f * val * (1.0f + erff(val * 0.70710678118654752f));
          outb[(size_t)m * N + n] = __float2bfloat16(gg);
        } else {
          if (bz == 0)
            outf[(size_t)m * N + n] = addsrc[(size_t)m * N + n] + bz2 + val;
          else
            po[(size_t)m * N + n] = __float2bfloat16(val);
        }
      }
    }
  }
}

// ---------- out[i] += (float)p[i], vectorized x4 ----------
__global__ __launch_bounds__(256)
void addp_kernel(float* __restrict__ out, const __hip_bfloat16* __restrict__ p) {
  const int i = (blockIdx.x * 256 + threadIdx.x) * 4;
  float4 o = *(const float4*)(out + i);
  const __hip_bfloat16* pp = p + i;
  o.x += (float)pp[0]; o.y += (float)pp[1]; o.z += (float)pp[2]; o.w += (float)pp[3];
  *(float4*)(out + i) = o;
}

// ---------- flash attention, paired q-tiles (i, 31-i), double-buffered K/V ----
__global__ __launch_bounds__(256)
void attn_kernel(const __hip_bfloat16* __restrict__ qb,
                 const __hip_bfloat16* __restrict__ kb,
                 const __hip_bfloat16* __restrict__ vt,
                 const float* __restrict__ alibi,
                 __hip_bfloat16* __restrict__ ctx) {
  __shared__ __align__(16) __hip_bfloat16 Kl[2][64 * 64];
  __shared__ __align__(16) __hip_bfloat16 Vl[2][64 * 64];   // [d][key]
  __shared__ __align__(16) __hip_bfloat16 Pl[4][16 * 64];   // per-wave P tile
  const int pi = blockIdx.x, h = blockIdx.y;
  const int qA = pi, qB = (Sq / 64 - 1) - pi;
  const int t = threadIdx.x, w = t >> 6, lane = t & 63, quad = lane >> 4, l16 = lane & 15;
  const __hip_bfloat16* qh = qb + (size_t)h * Sq * HDm;
  const __hip_bfloat16* kh = kb + (size_t)h * Sq * HDm;
  const __hip_bfloat16* vh = vt + (size_t)h * HDm * Sq;
  const float* al = alibi + (size_t)h * Sq;

  const int rA = qA * 64 + w * 16 + l16;
  const int rB = qB * 64 + w * 16 + l16;
  const bf16x8 qA0 = *(const bf16x8*)(qh + (size_t)rA * HDm + quad * 8);
  const bf16x8 qA1 = *(const bf16x8*)(qh + (size_t)rA * HDm + 32 + quad * 8);
  const bf16x8 qB0 = *(const bf16x8*)(qh + (size_t)rB * HDm + quad * 8);
  const bf16x8 qB1 = *(const bf16x8*)(qh + (size_t)rB * HDm + 32 + quad * 8);

  auto stageS = [&](int b, int s) {
    const int kbk = (s <= qA) ? s : s - qA - 1;
#pragma unroll
    for (int j = 0; j < 2; ++j) {
      int c = j * 256 + t;
      int row = c >> 3;
      int swz = (c & 7) ^ (row & 7);
      async_ld16(kh + (size_t)(kbk * 64 + row) * HDm + swz * 8, &Kl[b][c * 8]);
      async_ld16(vh + (size_t)row * Sq + kbk * 64 + swz * 8, &Vl[b][c * 8]);
    }
  };

  f32x4 o[4] = {};
  float m_i[4], l_i[4];
#pragma unroll
  for (int r = 0; r < 4; ++r) { m_i[r] = -3e38f; l_i[r] = 0.f; }

  const int total = qA + qB + 2;  // 33
  stageS(0, 0);
  int buf = 0;
  for (int s = 0; s < total; ++s, buf ^= 1) {
    __syncthreads();
    if (s + 1 < total) stageS(buf ^ 1, s + 1);
    const bool ph = (s > qA);
    const int kbk = ph ? s - qA - 1 : s;
    const int qblk = ph ? qB : qA;
    const bf16x8 a0 = ph ? qB0 : qA0;
    const bf16x8 a1 = ph ? qB1 : qA1;

    f32x4 sf[4];
    const f32x4 zero = {};
#pragma unroll
    for (int nt = 0; nt < 4; ++nt) {
      int row = nt * 16 + l16;
      bf16x8 kf0 = *(const bf16x8*)(&Kl[buf][row * 64 + ((quad ^ (row & 7)) << 3)]);
      bf16x8 kf1 = *(const bf16x8*)(&Kl[buf][row * 64 + (((4 + quad) ^ (row & 7)) << 3)]);
      sf[nt] = __builtin_amdgcn_mfma_f32_16x16x32_bf16(a0, kf0, zero, 0, 0, 0);
      sf[nt] = __builtin_amdgcn_mfma_f32_16x16x32_bf16(a1, kf1, sf[nt], 0, 0, 0);
    }
    const bool diag = (kbk == qblk);
    float mrow[4] = {-3e38f, -3e38f, -3e38f, -3e38f};
#pragma unroll
    for (int nt = 0; nt < 4; ++nt) {
      const float ab = al[kbk * 64 + nt * 16 + l16] * 0.125f;
      const int kcol = nt * 16 + l16;
#pragma unroll
      for (int r = 0; r < 4; ++r) {
        float vv = sf[nt][r] + ab;
        if (diag && kcol > w * 16 + quad * 4 + r) vv = -3e38f;
        sf[nt][r] = vv;
        mrow[r] = fmaxf(mrow[r], vv);
      }
    }
#pragma unroll
    for (int off = 8; off > 0; off >>= 1)
#pragma unroll
      for (int r = 0; r < 4; ++r)
        mrow[r] = fmaxf(mrow[r], __shfl_xor(mrow[r], off, 64));
    float alpha[4], rs[4], p[4][4];
#pragma unroll
    for (int r = 0; r < 4; ++r) {
      float mn = fmaxf(m_i[r], mrow[r]);
      alpha[r] = __expf(m_i[r] - mn);
      m_i[r] = mn;
    }
#pragma unroll
    for (int nt = 0; nt < 4; ++nt)
#pragma unroll
      for (int r = 0; r < 4; ++r) p[nt][r] = __expf(sf[nt][r] - m_i[r]);
#pragma unroll
    for (int r = 0; r < 4; ++r) rs[r] = p[0][r] + p[1][r] + p[2][r] + p[3][r];
#pragma unroll
    for (int off = 8; off > 0; off >>= 1)
#pragma unroll
      for (int r = 0; r < 4; ++r) rs[r] += __shfl_xor(rs[r], off, 64);
#pragma unroll
    for (int r = 0; r < 4; ++r) l_i[r] = l_i[r] * alpha[r] + rs[r];
#pragma unroll
    for (int dt = 0; dt < 4; ++dt)
#pragma unroll
      for (int r = 0; r < 4; ++r) o[dt][r] *= alpha[r];
    __hip_bfloat16* pw = &Pl[w][0];
#pragma unroll
    for (int nt = 0; nt < 4; ++nt)
#pragma unroll
      for (int r = 0; r < 4; ++r) {
        int prow = quad * 4 + r;
        int e = nt * 16 + l16;
        int c16 = e >> 3;
        pw[prow * 64 + ((c16 ^ (prow & 7)) << 3) + (e & 7)] = __float2bfloat16(p[nt][r]);
      }
    asm volatile("s_waitcnt lgkmcnt(0)" ::: "memory");
    const bf16x8 pa0 = *(const bf16x8*)(pw + l16 * 64 + ((quad ^ (l16 & 7)) << 3));
    const bf16x8 pa1 = *(const bf16x8*)(pw + l16 * 64 + (((4 + quad) ^ (l16 & 7)) << 3));
#pragma unroll
    for (int dt = 0; dt < 4; ++dt) {
      int row = dt * 16 + l16;
      bf16x8 v0 = *(const bf16x8*)(&Vl[buf][row * 64 + ((quad ^ (row & 7)) << 3)]);
      bf16x8 v1 = *(const bf16x8*)(&Vl[buf][row * 64 + (((4 + quad) ^ (row & 7)) << 3)]);
      o[dt] = __builtin_amdgcn_mfma_f32_16x16x32_bf16(pa0, v0, o[dt], 0, 0, 0);
      o[dt] = __builtin_amdgcn_mfma_f32_16x16x32_bf16(pa1, v1, o[dt], 0, 0, 0);
    }
    if (s == qA) {
#pragma unroll
      for (int dt = 0; dt < 4; ++dt)
#pragma unroll
        for (int r = 0; r < 4; ++r) {
          int srow = qA * 64 + w * 16 + quad * 4 + r;
          ctx[(size_t)srow * Dm + h * HDm + dt * 16 + l16] =
              __float2bfloat16(o[dt][r] / l_i[r]);
          o[dt][r] = 0.f;
        }
#pragma unroll
      for (int r = 0; r < 4; ++r) { m_i[r] = -3e38f; l_i[r] = 0.f; }
    }
  }
#pragma unroll
  for (int dt = 0; dt < 4; ++dt)
#pragma unroll
    for (int r = 0; r < 4; ++r) {
      int srow = qB * 64 + w * 16 + quad * 4 + r;
      ctx[(size_t)srow * Dm + h * HDm + dt * 16 + l16] =
          __float2bfloat16(o[dt][r] / l_i[r]);
    }
}

extern "C" void kernel_launch(void* const* d_in, const int* in_sizes, int n_in,
                              void* d_out, int out_size, void* d_ws, size_t ws_size,
                              hipStream_t stream) {
  const float* x     = (const float*)d_in[0];
  const float* alibi = (const float*)d_in[1];
  const float* ln1g  = (const float*)d_in[3];
  const float* ln1b  = (const float*)d_in[4];
  const float* ln2g  = (const float*)d_in[5];
  const float* ln2b  = (const float*)d_in[6];
  const float* wqkv  = (const float*)d_in[7];
  const float* bqkv  = (const float*)d_in[8];
  const float* wo    = (const float*)d_in[9];
  const float* bo    = (const float*)d_in[10];
  const float* w1    = (const float*)d_in[11];
  const float* b1    = (const float*)d_in[12];
  const float* w2    = (const float*)d_in[13];
  const float* b2    = (const float*)d_in[14];
  float* out = (float*)d_out;

  char* p = (char*)d_ws;
  auto alloc = [&](size_t bytes) {
    char* r = p;
    p += (bytes + 255) & ~(size_t)255;
    return r;
  };
  constexpr size_t SD2 = (size_t)Sq * Dm * 2;
  char* R2 = alloc((size_t)FFm * Dm * 2);
  char* R1 = alloc(4 * SD2);
  __hip_bfloat16* hb   = (__hip_bfloat16*)alloc(SD2);
  float*          resb = (float*)alloc((size_t)Sq * Dm * 4);

  __hip_bfloat16* wqkvT = (__hip_bfloat16*)R2;
  __hip_bfloat16* w1T   = (__hip_bfloat16*)R2;
  __hip_bfloat16* w2T   = (__hip_bfloat16*)R2;
  __hip_bfloat16* qbuf  = (__hip_bfloat16*)(R1 + 0 * SD2);
  __hip_bfloat16* kbuf  = (__hip_bfloat16*)(R1 + 1 * SD2);
  __hip_bfloat16* vtbuf = (__hip_bfloat16*)(R1 + 2 * SD2);
  __hip_bfloat16* ctxb  = (__hip_bfloat16*)(R1 + 3 * SD2);
  __hip_bfloat16* woT   = (__hip_bfloat16*)(R1 + 0 * SD2);  // after attn
  __hip_bfloat16* t1b   = (__hip_bfloat16*)R1;              // after proj
  __hip_bfloat16* part  = hb;                               // split-K partials

  // 1) wqkv transpose+cast, ln1
  tcast_kernel<<<dim3(3 * Dm / 64, Dm / 64), 256, 0, stream>>>(wqkv, wqkvT, Dm, 3 * Dm);
  ln_kernel<<<Sq, 256, 0, stream>>>(x, ln1g, ln1b, hb);
  // 2) QKV gemm
  gemm_kernel<0><<<dim3(3 * Dm / 128, Sq / 128), 256, 0, stream>>>(
      hb, wqkvT, 3 * Dm, Dm, Dm, bqkv, nullptr, nullptr, nullptr, qbuf, kbuf, vtbuf, nullptr);
  // 3) w1 transpose
  tcast_kernel<<<dim3(FFm / 64, Dm / 64), 256, 0, stream>>>(w1, w1T, Dm, FFm);
  // 4) flash attention (paired q-tiles, balanced)
  attn_kernel<<<dim3(Sq / 128, NH), 256, 0, stream>>>(qbuf, kbuf, vtbuf, alibi, ctxb);
  // 5) wo transpose into q slot
  tcast_kernel<<<dim3(Dm / 64, Dm / 64), 256, 0, stream>>>(wo, woT, Dm, Dm);
  // 6) attn proj + residual -> resb (fp32), split-K=2
  gemm_kernel<3><<<dim3(Dm / 128, Sq / 128, 2), 256, 0, stream>>>(
      ctxb, woT, Dm, Dm, Dm / 2, bo, x, resb, nullptr, nullptr, nullptr, nullptr, part);
  addp_kernel<<<(Sq * Dm) / 1024, 256, 0, stream>>>(resb, part);
  // 7) ln2
  ln_kernel<<<Sq, 256, 0, stream>>>(resb, ln2g, ln2b, hb);
  // 8) mlp up + gelu -> t1b
  gemm_kernel<2><<<dim3(FFm / 128, Sq / 128), 256, 0, stream>>>(
      hb, w1T, FFm, Dm, Dm, b1, nullptr, nullptr, t1b, nullptr, nullptr, nullptr, nullptr);
  // 9) w2 transpose
  tcast_kernel<<<dim3(Dm / 64, FFm / 64), 256, 0, stream>>>(w2, w2T, FFm, Dm);
  // 10) mlp down, split-K=2
  gemm_kernel<3><<<dim3(Dm / 128, Sq / 128, 2), 256, 0, stream>>>(
      t1b, w2T, Dm, FFm, FFm / 2, b2, resb, out, nullptr, nullptr, nullptr, nullptr, part);
  // 11) out += part
  addp_kernel<<<(Sq * Dm) / 1024, 256, 0, stream>>>(out, part);
}